// Round 10
// baseline (25.180 us; speedup 1.0000x reference)
//
#include <hip/hip_runtime.h>

#define LDSPTS 2048

__device__ __forceinline__ float exp2fast(float x) {
#if __has_builtin(__builtin_amdgcn_exp2f)
    return __builtin_amdgcn_exp2f(x);
#else
    return __expf(x * 0.6931471805599453f);
#endif
}
__device__ __forceinline__ float rsqfast(float x) {
#if __has_builtin(__builtin_amdgcn_rsqf)
    return __builtin_amdgcn_rsqf(x);
#else
    return rsqrtf(x);
#endif
}

// Block = 256 thr = 4 waves = 2 output points (pa) x 2 i-halves (ih), lane=i.
// TWO sequential passes over ONE staged 32KB tile (stage once, reuse in pass B):
//   pass 0: scale group {16,12,8,4,2,1,6,3}   (2 exp + 6 squarings)
//   pass 1: scale group {9,10,11,13,14,15,5,7} (6 exp + 2 squarings)
// (mu_{s'} = C/s' => e_{s'}^2 = e_{s'/2}; s' = global s + 1)
// acc[32] per pass (not 64) -> ~70 VGPR -> 4 blocks/CU (LDS-capped, 50% occ).
// Butterfly + epilogue tables verified in R3/R8 (both passed).
__global__ __launch_bounds__(256, 4) void sph_one(
    const float* __restrict__ f, const float* __restrict__ coords,
    const float* __restrict__ out_coords, const float* __restrict__ mu,
    const float* __restrict__ r_norms, const float* __restrict__ a0,
    const float* __restrict__ a1, float* __restrict__ out, int N, int A)
{
    __shared__ float4 sP[LDSPTS];          // 32 KB
    __shared__ float red[2][2][32];        // [pa][pass][value]

    const int tid  = threadIdx.x;
    const int lane = tid & 63;
    const int w    = tid >> 6;
    const int pa   = w >> 1;
    const int ih   = w & 1;
    const int a    = blockIdx.x * 2 + pa;
    const bool act = (a < A);
    const int ac   = act ? a : (A - 1);

    const float ox = out_coords[3 * ac + 0];   // wave-uniform -> SGPR
    const float oy = out_coords[3 * ac + 1];
    const float oz = out_coords[3 * ac + 2];

    const float L2E = 1.44269504088896340736f;
    const float kA0 = -L2E * mu[15], kA1 = -L2E * mu[11];           // s'=16,12
    const float kB0 = -L2E * mu[8],  kB1 = -L2E * mu[9];            // s'=9,10
    const float kB2 = -L2E * mu[10], kB3 = -L2E * mu[12];           // s'=11,13
    const float kB4 = -L2E * mu[13], kB5 = -L2E * mu[14];           // s'=14,15

    const bool onetile = (N <= LDSPTS);
    float totA = 0.f, totB = 0.f;
    float acc[32];

#pragma unroll
    for (int pass = 0; pass < 2; ++pass) {
#pragma unroll
        for (int j = 0; j < 32; ++j) acc[j] = 0.0f;

        for (int base = 0; base < N; base += LDSPTS) {
            const int seg = min(LDSPTS, N - base);
            if (!(onetile && pass == 1)) {      // tile already resident in pass B
                __syncthreads();
                const int segq = seg >> 2;
                const float4* fq = (const float4*)(f + base);
                const float4* cq = (const float4*)(coords + 3 * base);
                for (int j = tid; j < segq; j += 256) {
                    const float4 fv = fq[j];
                    const float4 c0 = cq[3 * j + 0];
                    const float4 c1 = cq[3 * j + 1];
                    const float4 c2 = cq[3 * j + 2];
                    sP[4 * j + 0] = make_float4(fv.x, c0.x, c0.y, c0.z);
                    sP[4 * j + 1] = make_float4(fv.y, c0.w, c1.x, c1.y);
                    sP[4 * j + 2] = make_float4(fv.z, c1.z, c1.w, c2.x);
                    sP[4 * j + 3] = make_float4(fv.w, c2.y, c2.z, c2.w);
                }
                for (int j = (segq << 2) + tid; j < seg; j += 256) {
                    const int gi = base + j;
                    sP[j] = make_float4(f[gi], coords[3 * gi + 0],
                                        coords[3 * gi + 1], coords[3 * gi + 2]);
                }
                __syncthreads();
            }
            if (act) {
                for (int t = lane + (ih << 6); t < seg; t += 128) {
                    const float4 p = sP[t];            // ds_read_b128
                    const float fi = p.x;
                    const float dx = p.y - ox;
                    const float dy = p.z - oy;
                    const float dz = p.w - oz;
                    const float r2 = fmaf(dx, dx, fmaf(dy, dy, dz * dz));
                    const float rinv = rsqfast(r2);
                    const float r  = r2 * rinv;
                    const float fr = fi * rinv;
                    const float fx = fr * dx, fy = fr * dy, fz = fr * dz;

                    float e[8];
                    if (pass == 0) {
                        e[0] = exp2fast(kA0 * r);      // s'=16
                        e[1] = exp2fast(kA1 * r);      // s'=12
                        e[2] = e[0] * e[0];            // 8
                        e[3] = e[2] * e[2];            // 4
                        e[4] = e[3] * e[3];            // 2
                        e[5] = e[4] * e[4];            // 1
                        e[6] = e[1] * e[1];            // 6
                        e[7] = e[6] * e[6];            // 3
                    } else {
                        e[0] = exp2fast(kB0 * r);      // 9
                        e[1] = exp2fast(kB1 * r);      // 10
                        e[2] = exp2fast(kB2 * r);      // 11
                        e[3] = exp2fast(kB3 * r);      // 13
                        e[4] = exp2fast(kB4 * r);      // 14
                        e[5] = exp2fast(kB5 * r);      // 15
                        e[6] = e[1] * e[1];            // 5
                        e[7] = e[4] * e[4];            // 7
                    }
#pragma unroll
                    for (int sl = 0; sl < 8; ++sl) {
                        acc[4 * sl + 0] = fmaf(e[sl], fi, acc[4 * sl + 0]);
                        acc[4 * sl + 1] = fmaf(e[sl], fx, acc[4 * sl + 1]);
                        acc[4 * sl + 2] = fmaf(e[sl], fy, acc[4 * sl + 2]);
                        acc[4 * sl + 3] = fmaf(e[sl], fz, acc[4 * sl + 3]);
                    }
                }
            }
        }

        // R3-verified value-split butterfly over 32 values; lane l -> value (l&31)
#pragma unroll
        for (int m = 16; m >= 1; m >>= 1) {
            const bool hi = (lane & m) != 0;
#pragma unroll
            for (int j = 0; j < m; ++j) {
                const float lo_v = acc[j];
                const float hi_v = acc[j + m];
                const float give = hi ? lo_v : hi_v;
                const float keep = hi ? hi_v : lo_v;
                acc[j] = keep + __shfl_xor(give, m, 64);
            }
        }
        const float tot = acc[0] + __shfl_xor(acc[0], 32, 64);
        if (act && ih == 1 && lane < 32) red[pa][pass][lane] = tot;
        if (pass == 0) totA = tot; else totB = tot;
    }

    __syncthreads();
    if (act && ih == 0 && lane < 32) {
        const int sl = lane >> 2;      // local scale slot 0..7
        const int cc = lane & 3;       // 0 = scalar, 1..3 = x/y/z
        {   // group A (pass 0): nibble table {15,11,7,3,1,0,5,2}
            const float sum = totA + red[pa][0][lane];
            const int s = (0x250137BFu >> (sl * 4)) & 0xF;
            float scale; int ov;
            if (cc == 0) { scale = r_norms[s] * a0[0];     ov = s; }
            else         { scale = r_norms[s] * a1[cc - 1]; ov = 16 + 3 * s + (cc - 1); }
            out[a * 64 + ov] = sum * scale;
        }
        {   // group B (pass 1): nibble table {8,9,10,12,13,14,4,6}
            const float sum = totB + red[pa][1][lane];
            const int s = (0x64EDCA98u >> (sl * 4)) & 0xF;
            float scale; int ov;
            if (cc == 0) { scale = r_norms[s] * a0[0];     ov = s; }
            else         { scale = r_norms[s] * a1[cc - 1]; ov = 16 + 3 * s + (cc - 1); }
            out[a * 64 + ov] = sum * scale;
        }
    }
}

extern "C" void kernel_launch(void* const* d_in, const int* in_sizes, int n_in,
                              void* d_out, int out_size, void* d_ws, size_t ws_size,
                              hipStream_t stream) {
    const float* f          = (const float*)d_in[0];
    const float* coords     = (const float*)d_in[1];
    const float* out_coords = (const float*)d_in[2];
    const float* mu         = (const float*)d_in[3];
    const float* r_norms    = (const float*)d_in[4];
    const float* a_norms_0  = (const float*)d_in[5];
    const float* a_norms_1  = (const float*)d_in[6];
    float* out = (float*)d_out;

    const int N = in_sizes[0];       // f is [B=1, N]
    const int A = in_sizes[2] / 3;   // out_coords is [B=1, A, 3]

    sph_one<<<(A + 1) / 2, 256, 0, stream>>>(f, coords, out_coords, mu, r_norms,
                                             a_norms_0, a_norms_1, out, N, A);
}

// Round 11
// 19.583 us; speedup vs baseline: 1.2858x; 1.2858x over previous
//
#include <hip/hip_runtime.h>

__device__ __forceinline__ float exp2fast(float x) {
#if __has_builtin(__builtin_amdgcn_exp2f)
    return __builtin_amdgcn_exp2f(x);
#else
    return __expf(x * 0.6931471805599453f);
#endif
}
__device__ __forceinline__ float rsqfast(float x) {
#if __has_builtin(__builtin_amdgcn_rsqf)
    return __builtin_amdgcn_rsqf(x);
#else
    return rsqrtf(x);
#endif
}

struct F3 { float x, y, z; };

// R6 compute shape (best so far) with the LDS stage DELETED:
//  - Block = 256 thr = 4 waves = 2 output points (pa) x 2 i-halves (ih); lane=i.
//  - Inputs (f 8KB + coords 24KB) are L1-resident: loads go straight from
//    global with a 1-deep register prefetch; no __syncthreads lockstep.
//  - All 16 scales per wave: 8 exp seeds (s'=16,12,9,10,11,13,14,15) +
//    squaring chain (mu_{s'} = C/s' => e_{s'/2} = e_{s'}^2).
//  - R1-verified 63-shuffle value-split butterfly: lane l ends with value l.
//  - LDS only for the 2x64 ih-combine (512 B).
__global__ __launch_bounds__(256, 4) void sph_one(
    const float* __restrict__ f, const float* __restrict__ coords,
    const float* __restrict__ out_coords, const float* __restrict__ mu,
    const float* __restrict__ r_norms, const float* __restrict__ a0,
    const float* __restrict__ a1, float* __restrict__ out, int N, int A)
{
    __shared__ float red[2][64];

    const int tid  = threadIdx.x;
    const int lane = tid & 63;
    const int w    = tid >> 6;
    const int pa   = w >> 1;
    const int ih   = w & 1;
    const int a    = blockIdx.x * 2 + pa;
    const bool act = (a < A);
    const int ac   = act ? a : (A - 1);

    const float ox = out_coords[3 * ac + 0];   // wave-uniform -> SGPR
    const float oy = out_coords[3 * ac + 1];
    const float oz = out_coords[3 * ac + 2];

    const float L2E = 1.44269504088896340736f;
    const float k16 = -L2E * mu[15], k12 = -L2E * mu[11];
    const float k9  = -L2E * mu[8],  k10 = -L2E * mu[9],  k11 = -L2E * mu[10];
    const float k13 = -L2E * mu[12], k14 = -L2E * mu[13], k15 = -L2E * mu[14];

    float acc[64];
#pragma unroll
    for (int j = 0; j < 64; ++j) acc[j] = 0.0f;

    const F3* c3 = (const F3*)coords;

    // 1-deep prefetch pipeline over t = lane + ih*64, stride 128
    int t = lane + (ih << 6);
    float cf = 0.f, cx = 0.f, cy = 0.f, cz = 0.f;
    if (act && t < N) {
        cf = f[t];
        const F3 p = c3[t];
        cx = p.x; cy = p.y; cz = p.z;
    }
    while (act && t < N) {
        const int tn = t + 128;
        const bool more = (tn < N);
        float nf = 0.f, nx = 0.f, ny = 0.f, nz = 0.f;
        if (more) {
            nf = f[tn];
            const F3 p = c3[tn];
            nx = p.x; ny = p.y; nz = p.z;
        }

        const float dx = cx - ox, dy = cy - oy, dz = cz - oz;
        const float r2 = fmaf(dx, dx, fmaf(dy, dy, dz * dz));
        const float rinv = rsqfast(r2);
        const float r  = r2 * rinv;
        const float fr = cf * rinv;
        const float fx = fr * dx, fy = fr * dy, fz = fr * dz;

        float e[16];                  // e[s] for global scale s (s' = s+1)
        e[15] = exp2fast(k16 * r);
        e[11] = exp2fast(k12 * r);
        e[8]  = exp2fast(k9  * r);
        e[9]  = exp2fast(k10 * r);
        e[10] = exp2fast(k11 * r);
        e[12] = exp2fast(k13 * r);
        e[13] = exp2fast(k14 * r);
        e[14] = exp2fast(k15 * r);
        e[7] = e[15] * e[15];         // s'=8
        e[3] = e[7]  * e[7];          // 4
        e[1] = e[3]  * e[3];          // 2
        e[0] = e[1]  * e[1];          // 1
        e[5] = e[11] * e[11];         // 6
        e[2] = e[5]  * e[5];          // 3
        e[4] = e[9]  * e[9];          // 5
        e[6] = e[13] * e[13];         // 7
#pragma unroll
        for (int s = 0; s < 16; ++s) {
            acc[4 * s + 0] = fmaf(e[s], cf, acc[4 * s + 0]);
            acc[4 * s + 1] = fmaf(e[s], fx, acc[4 * s + 1]);
            acc[4 * s + 2] = fmaf(e[s], fy, acc[4 * s + 2]);
            acc[4 * s + 3] = fmaf(e[s], fz, acc[4 * s + 3]);
        }

        t = tn; cf = nf; cx = nx; cy = ny; cz = nz;
    }

    // R1-verified value-split butterfly: lane l ends with full sum of value l.
#pragma unroll
    for (int m = 32; m >= 1; m >>= 1) {
        const bool hi = (lane & m) != 0;
#pragma unroll
        for (int j = 0; j < m; ++j) {
            const float lo_v = acc[j];
            const float hi_v = acc[j + m];
            const float give = hi ? lo_v : hi_v;
            const float keep = hi ? hi_v : lo_v;
            acc[j] = keep + __shfl_xor(give, m, 64);
        }
    }
    const float tot = acc[0];

    if (act && ih == 1) red[pa][lane] = tot;
    __syncthreads();
    if (act && ih == 0) {
        const float sum = tot + red[pa][lane];
        const int s = lane >> 2;
        const int c = lane & 3;
        float scale; int ov;
        if (c == 0) { scale = r_norms[s] * a0[0];     ov = s; }
        else        { scale = r_norms[s] * a1[c - 1]; ov = 16 + 3 * s + (c - 1); }
        out[a * 64 + ov] = sum * scale;
    }
}

extern "C" void kernel_launch(void* const* d_in, const int* in_sizes, int n_in,
                              void* d_out, int out_size, void* d_ws, size_t ws_size,
                              hipStream_t stream) {
    const float* f          = (const float*)d_in[0];
    const float* coords     = (const float*)d_in[1];
    const float* out_coords = (const float*)d_in[2];
    const float* mu         = (const float*)d_in[3];
    const float* r_norms    = (const float*)d_in[4];
    const float* a_norms_0  = (const float*)d_in[5];
    const float* a_norms_1  = (const float*)d_in[6];
    float* out = (float*)d_out;

    const int N = in_sizes[0];       // f is [B=1, N]
    const int A = in_sizes[2] / 3;   // out_coords is [B=1, A, 3]

    sph_one<<<(A + 1) / 2, 256, 0, stream>>>(f, coords, out_coords, mu, r_norms,
                                             a_norms_0, a_norms_1, out, N, A);
}